// Round 6
// baseline (67.891 us; speedup 1.0000x reference)
//
#include <hip/hip_runtime.h>
#include <cstdint>
#include <cstddef>

// Problem constants (from reference)
constexpr int B = 8, C = 96, N = 3136, K = 18;
constexpr float C1c = 1e-6f, C2c = 1e-6f;

__device__ inline float readlane_f(float v, int l) {
  return __builtin_bit_cast(float,
                            __builtin_amdgcn_readlane(__builtin_bit_cast(int, v), l));
}

// ---------------------------------------------------------------------------
// Kernel A (fused): transpose x,xp [B,C,N]->[B,N,C] AND per-column channel
// sums of x (cstat = {Σx, Σx²}). XCD-pinned: blockIdx&7 == batch.
// ---------------------------------------------------------------------------
__global__ __launch_bounds__(256) void fusedT_kernel(
    const float* __restrict__ x, const float* __restrict__ xp,
    float* __restrict__ xT, float* __restrict__ xpT,
    float2* __restrict__ cstat) {
  __shared__ float t0[C][33];
  __shared__ float t1[C][33];
  __shared__ float red1[8][33];
  __shared__ float red2[8][33];
  const int bid = blockIdx.x;
  const int b = bid & 7;              // XCD pin
  const int n0 = (bid >> 3) * 32;
  const int tx = threadIdx.x & 31;
  const int ty = threadIdx.x >> 5;

  const float* xb = x + (size_t)b * C * N;
  const float* xpb = xp + (size_t)b * C * N;
  float s = 0.f, s2 = 0.f;
#pragma unroll
  for (int st = 0; st < 12; ++st) {
    const int c = st * 8 + ty;
    const float v = xb[(size_t)c * N + n0 + tx];
    const float u = xpb[(size_t)c * N + n0 + tx];
    t0[c][tx] = v;
    t1[c][tx] = u;
    s += v;
    s2 += v * v;
  }
  red1[ty][tx] = s;
  red2[ty][tx] = s2;
  __syncthreads();

  float* xTb = xT + (size_t)b * N * C;
  float* xpTb = xpT + (size_t)b * N * C;
  const int tid = threadIdx.x;
#pragma unroll
  for (int r = 0; r < 12; ++r) {
    const int f = r * 256 + tid;      // f = nl*96 + c, coalesced
    const int nl = f / 96;
    const int c = f - nl * 96;
    xTb[(size_t)(n0 + nl) * C + c] = t0[c][nl];
    xpTb[(size_t)(n0 + nl) * C + c] = t1[c][nl];
  }
  if (ty == 0) {
    float S = 0.f, S2 = 0.f;
#pragma unroll
    for (int yy = 0; yy < 8; ++yy) {
      S += red1[yy][tx];
      S2 += red2[yy][tx];
    }
    cstat[(size_t)b * N + n0 + tx] = make_float2(S, S2);
  }
}

// ---------------------------------------------------------------------------
// Kernel B: main fused kernel. One wave per TWO centers (n0, n0+1);
// XCD-pinned (blockIdx&7 = batch). Two centers give each wave two fully
// independent load/compute chains (2x memory-level parallelism).
//   Phase 1 (per center): group-parallel dots — lane = 8g+w; group g owns
//     k = {g,g+8,g+16}; lane loads 12 channels (3x float4); 3-level
//     butterfly in-group; group-parallel sff. 6 independent rounds total.
//   Phase 2: xp accumulation in the 48-lane float2 layout with an explicit
//     4-slot, prefetch-2 software pipeline (indices compile-time after full
//     unroll). sff broadcast via readlane at use-site.
// ---------------------------------------------------------------------------
__global__ __launch_bounds__(256, 4) void ssim_main_kernel(
    const float* __restrict__ xT, const float* __restrict__ xpT,
    const float2* __restrict__ cstat, const int* __restrict__ eidx,
    float* __restrict__ outT) {
  const int wave = threadIdx.x >> 6;
  const int lane = threadIdx.x & 63;
  const int b = blockIdx.x & 7;       // XCD pin: batch == blockIdx % 8
  const int tile = blockIdx.x >> 3;   // 0..391
  const int n0 = tile * 8 + wave * 2;
  const int n1 = n0 + 1;

  // lanes 0..17 -> j_k (edge_index[0]), lanes 18..35 -> i_k (edge_index[1])
  int myidx0 = 0, myidx1 = 0;
  if (lane < 36) {
    const int s = (lane >= 18) ? 1 : 0;
    const int k = lane - 18 * s;
    const size_t base = ((size_t)(s * B + b) * N) * K + k;
    myidx0 = eidx[base + (size_t)n0 * K];
    myidx1 = eidx[base + (size_t)n1 * K];
  }

  const float* xb = xT + (size_t)b * N * C;
  const float2* cs = cstat + (size_t)b * N;
  const int g = lane >> 3;
  const int w = lane & 7;

  // ---- Phase 1: 6 independent group-parallel rounds (3 per center) -------
  auto do_round = [&](int myidx, int r) -> float {
    int k = r * 8 + g;
    if (k > K - 1) k = K - 1;         // round 2, groups 2..7: redundant k=17
    const int cj = __shfl(myidx, k, 64);
    const int ci = __shfl(myidx, 18 + k, 64);
    const float* pi = xb + (size_t)ci * C + w * 12;
    const float* pj = xb + (size_t)cj * C + w * 12;
    const float4 a0 = *(const float4*)pi;
    const float4 a1 = *(const float4*)(pi + 4);
    const float4 a2 = *(const float4*)(pi + 8);
    const float4 q0 = *(const float4*)pj;
    const float4 q1 = *(const float4*)(pj + 4);
    const float4 q2 = *(const float4*)(pj + 8);
    float p = a0.x * q0.x + a0.y * q0.y + a0.z * q0.z + a0.w * q0.w;
    p += a1.x * q1.x + a1.y * q1.y + a1.z * q1.z + a1.w * q1.w;
    p += a2.x * q2.x + a2.y * q2.y + a2.z * q2.z + a2.w * q2.w;
    p += __shfl_xor(p, 1, 64);        // butterfly within the 8-lane group
    p += __shfl_xor(p, 2, 64);
    p += __shfl_xor(p, 4, 64);

    const float2 si = cs[ci];
    const float2 sj = cs[cj];
    const float mi = si.x * (1.0f / C), mj = sj.x * (1.0f / C);
    const float vi = si.y * (1.0f / C) - mi * mi;
    const float vj = sj.y * (1.0f / C) - mj * mj;
    const float cov = p * (1.0f / C) - mi * mj;
    const float S1 =
        (2.f * mi * mj + C1c) * __builtin_amdgcn_rcpf(mi * mi + mj * mj + C1c);
    const float S2 = (2.f * cov + C2c) * __builtin_amdgcn_rcpf(vi + vj + C2c);
    return 1.f - S1 * S2;
  };
  const float s00 = do_round(myidx0, 0);
  const float s01 = do_round(myidx0, 1);
  const float s02 = do_round(myidx0, 2);
  const float s10 = do_round(myidx1, 0);
  const float s11 = do_round(myidx1, 1);
  const float s12 = do_round(myidx1, 2);

  // ---- Phase 2: xp accumulation, 4-slot prefetch-2 pipeline --------------
  const float2* xpb2 = (const float2*)(xpT + (size_t)b * N * C);
  const int l48 = (lane < 48) ? lane : 47;  // lanes 48-63 duplicate lane 47

  float2 A0[4], Q0[4], A1[4], Q1[4];
#pragma unroll
  for (int k = 0; k < 2; ++k) {       // prologue: k = 0, 1
    A0[k] = xpb2[(size_t)__builtin_amdgcn_readlane(myidx0, 18 + k) * 48 + l48];
    Q0[k] = xpb2[(size_t)__builtin_amdgcn_readlane(myidx0, k) * 48 + l48];
    A1[k] = xpb2[(size_t)__builtin_amdgcn_readlane(myidx1, 18 + k) * 48 + l48];
    Q1[k] = xpb2[(size_t)__builtin_amdgcn_readlane(myidx1, k) * 48 + l48];
  }

  float tx0 = 0.f, ty0 = 0.f, ax0 = 0.f, ay0 = 0.f;
  float tx1 = 0.f, ty1 = 0.f, ax1 = 0.f, ay1 = 0.f;
#pragma unroll
  for (int k = 0; k < K; ++k) {
    if (k + 2 < K) {                  // prefetch k+2 into slot (k+2)&3
      const int nx = (k + 2) & 3;
      A0[nx] =
          xpb2[(size_t)__builtin_amdgcn_readlane(myidx0, 20 + k) * 48 + l48];
      Q0[nx] = xpb2[(size_t)__builtin_amdgcn_readlane(myidx0, k + 2) * 48 + l48];
      A1[nx] =
          xpb2[(size_t)__builtin_amdgcn_readlane(myidx1, 20 + k) * 48 + l48];
      Q1[nx] = xpb2[(size_t)__builtin_amdgcn_readlane(myidx1, k + 2) * 48 + l48];
    }
    const int cur = k & 3;
    const float sf0 = readlane_f(k < 8 ? s00 : k < 16 ? s01 : s02, (k & 7) * 8);
    const float sf1 = readlane_f(k < 8 ? s10 : k < 16 ? s11 : s12, (k & 7) * 8);
    tx0 += A0[cur].x + Q0[cur].x;
    ty0 += A0[cur].y + Q0[cur].y;
    ax0 = fmaf(fabsf(A0[cur].x - Q0[cur].x), sf0, ax0);
    ay0 = fmaf(fabsf(A0[cur].y - Q0[cur].y), sf0, ay0);
    tx1 += A1[cur].x + Q1[cur].x;
    ty1 += A1[cur].y + Q1[cur].y;
    ax1 = fmaf(fabsf(A1[cur].x - Q1[cur].x), sf1, ax1);
    ay1 = fmaf(fabsf(A1[cur].y - Q1[cur].y), sf1, ay1);
  }

  if (lane < 48) {
    float2* ob0 = (float2*)(outT + ((size_t)b * N + n0) * C);
    ob0[lane] = make_float2(tx0 + ax0, ty0 + ay0);
    float2* ob1 = (float2*)(outT + ((size_t)b * N + n1) * C);
    ob1[lane] = make_float2(tx1 + ax1, ty1 + ay1);
  }
}

// ---------------------------------------------------------------------------
// Kernel C: transpose back outT [B,N,C] -> out [B,C,N], XCD-pinned.
// ---------------------------------------------------------------------------
__global__ __launch_bounds__(256) void transpose_back_kernel(
    const float* __restrict__ outT, float* __restrict__ out) {
  __shared__ float t[32][33];
  const int bid = blockIdx.x;
  const int b = bid & 7;              // XCD pin
  const int rest = bid >> 3;          // 0..293
  const int cb = rest / 98;           // 0..2
  const int nb = rest - cb * 98;      // 0..97
  const int n0 = nb * 32, c0 = cb * 32;
  const int tx = threadIdx.x & 31, ty = threadIdx.x >> 5;
  const float* ib = outT + (size_t)b * N * C;
#pragma unroll
  for (int i = 0; i < 4; ++i) {
    const int nn = n0 + ty + i * 8;
    t[ty + i * 8][tx] = ib[(size_t)nn * C + c0 + tx];
  }
  __syncthreads();
  float* ob = out + (size_t)b * C * N;
#pragma unroll
  for (int i = 0; i < 4; ++i) {
    const int c = c0 + ty + i * 8;
    ob[(size_t)c * N + n0 + tx] = t[tx][ty + i * 8];
  }
}

// ---------------------------------------------------------------------------
// Fallback (only used if ws_size is too small): slow but correct.
// ---------------------------------------------------------------------------
__global__ void fallback_kernel(const float* __restrict__ x,
                                const float* __restrict__ xp,
                                const int* __restrict__ e,
                                float* __restrict__ out) {
  const int gn = blockIdx.x * 64 + threadIdx.x;
  if (gn >= B * N) return;
  const int b = gn / N;
  const int n = gn - b * N;
  const float* xb = x + (size_t)b * C * N;
  const float* xpb = xp + (size_t)b * C * N;
  int ii[K], jj[K];
  float sff[K];
#pragma unroll
  for (int k = 0; k < K; ++k) {
    jj[k] = e[((size_t)(0 * B + b) * N + n) * K + k];
    ii[k] = e[((size_t)(1 * B + b) * N + n) * K + k];
    float si = 0, sj = 0, sii = 0, sjj = 0, sij = 0;
    for (int c = 0; c < C; ++c) {
      const float a = xb[(size_t)c * N + ii[k]];
      const float q = xb[(size_t)c * N + jj[k]];
      si += a; sj += q; sii += a * a; sjj += q * q; sij += a * q;
    }
    const float mi = si * (1.f / C), mj = sj * (1.f / C);
    const float vi = sii * (1.f / C) - mi * mi;
    const float vj = sjj * (1.f / C) - mj * mj;
    const float cov = sij * (1.f / C) - mi * mj;
    const float S1 = (2.f * mi * mj + C1c) / (mi * mi + mj * mj + C1c);
    const float S2 = (2.f * cov + C2c) / (vi + vj + C2c);
    sff[k] = 1.f - S1 * S2;
  }
  for (int c = 0; c < C; ++c) {
    float acc = 0.f;
#pragma unroll
    for (int k = 0; k < K; ++k) {
      const float a = xpb[(size_t)c * N + ii[k]];
      const float q = xpb[(size_t)c * N + jj[k]];
      acc += a + q + fabsf(a - q) * sff[k];
    }
    out[((size_t)b * C + c) * N + n] = acc;
  }
}

// ---------------------------------------------------------------------------
extern "C" void kernel_launch(void* const* d_in, const int* in_sizes, int n_in,
                              void* d_out, int out_size, void* d_ws, size_t ws_size,
                              hipStream_t stream) {
  const float* x = (const float*)d_in[0];
  const float* xp = (const float*)d_in[1];
  const int* e = (const int*)d_in[2];
  float* out = (float*)d_out;

  const size_t nBNC = (size_t)B * N * C;
  const size_t nBN = (size_t)B * N;
  const size_t need = 3 * nBNC * sizeof(float) + nBN * sizeof(float2);

  if (ws_size >= need) {
    float* ws = (float*)d_ws;
    float* xT = ws;
    float* xpT = xT + nBNC;
    float* outT = xpT + nBNC;
    float2* cstat = (float2*)(outT + nBNC);

    fusedT_kernel<<<8 * (N / 32), 256, 0, stream>>>(x, xp, xT, xpT, cstat);
    ssim_main_kernel<<<(B * N) / 8, 256, 0, stream>>>(xT, xpT, cstat, e, outT);
    transpose_back_kernel<<<8 * 3 * (N / 32), 256, 0, stream>>>(outT, out);
  } else {
    fallback_kernel<<<(B * N + 63) / 64, 64, 0, stream>>>(x, xp, e, out);
  }
}

// Round 7
// 59.678 us; speedup vs baseline: 1.1376x; 1.1376x over previous
//
#include <hip/hip_runtime.h>
#include <cstdint>
#include <cstddef>

// Problem constants (from reference)
constexpr int B = 8, C = 96, N = 3136, K = 18;
constexpr float C1c = 1e-6f, C2c = 1e-6f;

// ---------------------------------------------------------------------------
// Kernel A (fused): transpose x,xp [B,C,N]->[B,N,C] AND per-column channel
// sums of x (cstat = {Σx, Σx²}). XCD-pinned: blockIdx&7 == batch.
// ---------------------------------------------------------------------------
__global__ __launch_bounds__(256) void fusedT_kernel(
    const float* __restrict__ x, const float* __restrict__ xp,
    float* __restrict__ xT, float* __restrict__ xpT,
    float2* __restrict__ cstat) {
  __shared__ float t0[C][33];
  __shared__ float t1[C][33];
  __shared__ float red1[8][33];
  __shared__ float red2[8][33];
  const int bid = blockIdx.x;
  const int b = bid & 7;              // XCD pin
  const int n0 = (bid >> 3) * 32;
  const int tx = threadIdx.x & 31;
  const int ty = threadIdx.x >> 5;

  const float* xb = x + (size_t)b * C * N;
  const float* xpb = xp + (size_t)b * C * N;
  float s = 0.f, s2 = 0.f;
#pragma unroll
  for (int st = 0; st < 12; ++st) {
    const int c = st * 8 + ty;
    const float v = xb[(size_t)c * N + n0 + tx];
    const float u = xpb[(size_t)c * N + n0 + tx];
    t0[c][tx] = v;
    t1[c][tx] = u;
    s += v;
    s2 += v * v;
  }
  red1[ty][tx] = s;
  red2[ty][tx] = s2;
  __syncthreads();

  float* xTb = xT + (size_t)b * N * C;
  float* xpTb = xpT + (size_t)b * N * C;
  const int tid = threadIdx.x;
#pragma unroll
  for (int r = 0; r < 12; ++r) {
    const int f = r * 256 + tid;      // f = nl*96 + c, coalesced
    const int nl = f / 96;
    const int c = f - nl * 96;
    xTb[(size_t)(n0 + nl) * C + c] = t0[c][nl];
    xpTb[(size_t)(n0 + nl) * C + c] = t1[c][nl];
  }
  if (ty == 0) {
    float S = 0.f, S2 = 0.f;
#pragma unroll
    for (int yy = 0; yy < 8; ++yy) {
      S += red1[yy][tx];
      S2 += red2[yy][tx];
    }
    cstat[(size_t)b * N + n0 + tx] = make_float2(S, S2);
  }
}

// ---------------------------------------------------------------------------
// Kernel B: main fused kernel, single-phase. One wave per (b,n); XCD-pinned
// (blockIdx&7 = batch). Lane = 8g+w; group g owns k = {g, g+8, g+16}.
// Per round, each lane loads x_i, x_j, xp_i, xp_j for its 12 channels
// (12 independent float4 loads in ONE basic block -> real MLP), computes the
// dot (3-level in-group butterfly), sff (group-parallel, consumed in-place,
// no SGPR broadcast), and immediately accumulates the xp output term into a
// per-lane 12-float accumulator. Redundant k (r=2, g>=2) is zero-masked.
// Finally an 8-way cross-group reduction via LDS [96][9] (2-way conflicts
// max) and a direct strided write to out[B,C,N] (R3 measured: no WRITE
// inflation from this scatter; absorbed by XCD-local L2).
// ---------------------------------------------------------------------------
__global__ __launch_bounds__(256, 4) void ssim_main_kernel(
    const float* __restrict__ xT, const float* __restrict__ xpT,
    const float2* __restrict__ cstat, const int* __restrict__ eidx,
    float* __restrict__ out) {
  __shared__ float red[4][C][9];      // [wave][channel][group], pad 9
  const int wave = threadIdx.x >> 6;
  const int lane = threadIdx.x & 63;
  const int b = blockIdx.x & 7;       // XCD pin: batch == blockIdx % 8
  const int tile = blockIdx.x >> 3;
  const int n = tile * 4 + wave;

  // lanes 0..17 -> j_k (edge_index[0]), lanes 18..35 -> i_k (edge_index[1])
  int myidx = 0;
  if (lane < 36) {
    const int s = (lane >= 18) ? 1 : 0;
    const int k = lane - 18 * s;
    myidx = eidx[((size_t)(s * B + b) * N + n) * K + k];
  }

  const float* xb = xT + (size_t)b * N * C;
  const float* xpb = xpT + (size_t)b * N * C;
  const float2* cs = cstat + (size_t)b * N;
  const int g = lane >> 3;
  const int w = lane & 7;

  float acc[12];
#pragma unroll
  for (int d = 0; d < 12; ++d) acc[d] = 0.f;

#pragma unroll
  for (int r = 0; r < 3; ++r) {
    int k = r * 8 + g;
    float mask = 1.f;
    if (k > K - 1) {                  // r=2, g>=2: duplicate k, masked out
      k = K - 1;
      mask = 0.f;
    }
    const int cj = __shfl(myidx, k, 64);
    const int ci = __shfl(myidx, 18 + k, 64);
    const float* xi = xb + (size_t)ci * C + w * 12;
    const float* xj = xb + (size_t)cj * C + w * 12;
    const float* pi = xpb + (size_t)ci * C + w * 12;
    const float* pj = xpb + (size_t)cj * C + w * 12;
    // 12 independent float4 loads + 2 float2 loads, one basic block
    const float4 a0 = *(const float4*)(xi);
    const float4 a1 = *(const float4*)(xi + 4);
    const float4 a2 = *(const float4*)(xi + 8);
    const float4 q0 = *(const float4*)(xj);
    const float4 q1 = *(const float4*)(xj + 4);
    const float4 q2 = *(const float4*)(xj + 8);
    const float4 u0 = *(const float4*)(pi);
    const float4 u1 = *(const float4*)(pi + 4);
    const float4 u2 = *(const float4*)(pi + 8);
    const float4 v0 = *(const float4*)(pj);
    const float4 v1 = *(const float4*)(pj + 4);
    const float4 v2 = *(const float4*)(pj + 8);
    const float2 si = cs[ci];
    const float2 sj = cs[cj];

    float p = a0.x * q0.x + a0.y * q0.y + a0.z * q0.z + a0.w * q0.w;
    p += a1.x * q1.x + a1.y * q1.y + a1.z * q1.z + a1.w * q1.w;
    p += a2.x * q2.x + a2.y * q2.y + a2.z * q2.z + a2.w * q2.w;
    p += __shfl_xor(p, 1, 64);        // in-group butterfly (8 lanes)
    p += __shfl_xor(p, 2, 64);
    p += __shfl_xor(p, 4, 64);

    const float mi = si.x * (1.0f / C), mj = sj.x * (1.0f / C);
    const float vi = si.y * (1.0f / C) - mi * mi;
    const float vj = sj.y * (1.0f / C) - mj * mj;
    const float cov = p * (1.0f / C) - mi * mj;
    const float S1 =
        (2.f * mi * mj + C1c) * __builtin_amdgcn_rcpf(mi * mi + mj * mj + C1c);
    const float S2 = (2.f * cov + C2c) * __builtin_amdgcn_rcpf(vi + vj + C2c);
    const float sff = 1.f - S1 * S2;
    const float sm = sff * mask;

    auto accum4 = [&](const float4& u, const float4& v, int base) {
      acc[base + 0] =
          fmaf(mask, u.x + v.x, fmaf(sm, fabsf(u.x - v.x), acc[base + 0]));
      acc[base + 1] =
          fmaf(mask, u.y + v.y, fmaf(sm, fabsf(u.y - v.y), acc[base + 1]));
      acc[base + 2] =
          fmaf(mask, u.z + v.z, fmaf(sm, fabsf(u.z - v.z), acc[base + 2]));
      acc[base + 3] =
          fmaf(mask, u.w + v.w, fmaf(sm, fabsf(u.w - v.w), acc[base + 3]));
    };
    accum4(u0, v0, 0);
    accum4(u1, v1, 4);
    accum4(u2, v2, 8);
  }

  // ---- cross-group reduction (wave-local LDS, no barrier needed) ---------
#pragma unroll
  for (int d = 0; d < 12; ++d) red[wave][w * 12 + d][g] = acc[d];

  float s1 = 0.f;
#pragma unroll
  for (int gg = 0; gg < 8; ++gg) s1 += red[wave][lane][gg];
  out[((size_t)b * C + lane) * N + n] = s1;
  if (lane < 32) {
    float s2 = 0.f;
#pragma unroll
    for (int gg = 0; gg < 8; ++gg) s2 += red[wave][lane + 64][gg];
    out[((size_t)b * C + lane + 64) * N + n] = s2;
  }
}

// ---------------------------------------------------------------------------
// Fallback (only used if ws_size is too small): slow but correct.
// ---------------------------------------------------------------------------
__global__ void fallback_kernel(const float* __restrict__ x,
                                const float* __restrict__ xp,
                                const int* __restrict__ e,
                                float* __restrict__ out) {
  const int gn = blockIdx.x * 64 + threadIdx.x;
  if (gn >= B * N) return;
  const int b = gn / N;
  const int n = gn - b * N;
  const float* xb = x + (size_t)b * C * N;
  const float* xpb = xp + (size_t)b * C * N;
  int ii[K], jj[K];
  float sff[K];
#pragma unroll
  for (int k = 0; k < K; ++k) {
    jj[k] = e[((size_t)(0 * B + b) * N + n) * K + k];
    ii[k] = e[((size_t)(1 * B + b) * N + n) * K + k];
    float si = 0, sj = 0, sii = 0, sjj = 0, sij = 0;
    for (int c = 0; c < C; ++c) {
      const float a = xb[(size_t)c * N + ii[k]];
      const float q = xb[(size_t)c * N + jj[k]];
      si += a; sj += q; sii += a * a; sjj += q * q; sij += a * q;
    }
    const float mi = si * (1.f / C), mj = sj * (1.f / C);
    const float vi = sii * (1.f / C) - mi * mi;
    const float vj = sjj * (1.f / C) - mj * mj;
    const float cov = sij * (1.f / C) - mi * mj;
    const float S1 = (2.f * mi * mj + C1c) / (mi * mi + mj * mj + C1c);
    const float S2 = (2.f * cov + C2c) / (vi + vj + C2c);
    sff[k] = 1.f - S1 * S2;
  }
  for (int c = 0; c < C; ++c) {
    float acc = 0.f;
#pragma unroll
    for (int k = 0; k < K; ++k) {
      const float a = xpb[(size_t)c * N + ii[k]];
      const float q = xpb[(size_t)c * N + jj[k]];
      acc += a + q + fabsf(a - q) * sff[k];
    }
    out[((size_t)b * C + c) * N + n] = acc;
  }
}

// ---------------------------------------------------------------------------
extern "C" void kernel_launch(void* const* d_in, const int* in_sizes, int n_in,
                              void* d_out, int out_size, void* d_ws, size_t ws_size,
                              hipStream_t stream) {
  const float* x = (const float*)d_in[0];
  const float* xp = (const float*)d_in[1];
  const int* e = (const int*)d_in[2];
  float* out = (float*)d_out;

  const size_t nBNC = (size_t)B * N * C;
  const size_t nBN = (size_t)B * N;
  const size_t need = 2 * nBNC * sizeof(float) + nBN * sizeof(float2);

  if (ws_size >= need) {
    float* ws = (float*)d_ws;
    float* xT = ws;
    float* xpT = xT + nBNC;
    float2* cstat = (float2*)(xpT + nBNC);

    fusedT_kernel<<<8 * (N / 32), 256, 0, stream>>>(x, xp, xT, xpT, cstat);
    ssim_main_kernel<<<(B * N) / 4, 256, 0, stream>>>(xT, xpT, cstat, e, out);
  } else {
    fallback_kernel<<<(B * N + 63) / 64, 64, 0, stream>>>(x, xp, e, out);
  }
}

// Round 9
// 54.014 us; speedup vs baseline: 1.2569x; 1.1049x over previous
//
#include <hip/hip_runtime.h>
#include <cstdint>
#include <cstddef>

// Problem constants (from reference)
constexpr int B = 8, C = 96, N = 3136, K = 18;
constexpr float C1c = 1e-6f, C2c = 1e-6f;

// ---- inline-asm load / wait primitives ------------------------------------
#define GL4(dst, base, OFF)                                        \
  asm volatile("global_load_dwordx4 %0, %1, off offset:" #OFF     \
               : "=v"(dst)                                         \
               : "v"(base))
#define GL2(dst, base)                                             \
  asm volatile("global_load_dwordx2 %0, %1, off" : "=v"(dst) : "v"(base))

// Counted wait + scheduler fence (rule #18: the sched_barrier is what keeps
// dependent VALU from being hoisted above the wait).
#define VMWAIT(N)                                                  \
  asm volatile("s_waitcnt vmcnt(" #N ")" ::: "memory");            \
  __builtin_amdgcn_sched_barrier(0)

__device__ inline float dot4(const float4& a, const float4& b, float acc) {
  acc = fmaf(a.x, b.x, acc);
  acc = fmaf(a.y, b.y, acc);
  acc = fmaf(a.z, b.z, acc);
  acc = fmaf(a.w, b.w, acc);
  return acc;
}

// sum over the 8-lane group: xor1+xor2 via DPP quad_perm (VALU), xor4 via
// one ds_swizzle. All lanes of the group end with the full 8-lane sum.
__device__ inline float qsum8(float p) {
  int t = __builtin_amdgcn_update_dpp(0, __builtin_bit_cast(int, p), 0xB1,
                                      0xF, 0xF, true);  // quad_perm [1,0,3,2]
  p += __builtin_bit_cast(float, t);
  t = __builtin_amdgcn_update_dpp(0, __builtin_bit_cast(int, p), 0x4E, 0xF,
                                  0xF, true);           // quad_perm [2,3,0,1]
  p += __builtin_bit_cast(float, t);
  t = __builtin_amdgcn_ds_swizzle(__builtin_bit_cast(int, p), 0x101F);  // ^4
  p += __builtin_bit_cast(float, t);
  return p;
}

__device__ inline float sff_of(float p, float2 si, float2 sj) {
  const float mi = si.x * (1.0f / C), mj = sj.x * (1.0f / C);
  const float vi = si.y * (1.0f / C) - mi * mi;
  const float vj = sj.y * (1.0f / C) - mj * mj;
  const float cov = p * (1.0f / C) - mi * mj;
  const float S1 =
      (2.f * mi * mj + C1c) * __builtin_amdgcn_rcpf(mi * mi + mj * mj + C1c);
  const float S2 = (2.f * cov + C2c) * __builtin_amdgcn_rcpf(vi + vj + C2c);
  return 1.f - S1 * S2;
}

// ---------------------------------------------------------------------------
// Kernel A (fused): transpose x,xp [B,C,N]->[B,N,C] AND per-column channel
// sums of x (cstat = {Σx, Σx²}). XCD-pinned: blockIdx&7 == batch.
// ---------------------------------------------------------------------------
__global__ __launch_bounds__(256) void fusedT_kernel(
    const float* __restrict__ x, const float* __restrict__ xp,
    float* __restrict__ xT, float* __restrict__ xpT,
    float2* __restrict__ cstat) {
  __shared__ float t0[C][33];
  __shared__ float t1[C][33];
  __shared__ float red1[8][33];
  __shared__ float red2[8][33];
  const int bid = blockIdx.x;
  const int b = bid & 7;              // XCD pin
  const int n0 = (bid >> 3) * 32;
  const int tx = threadIdx.x & 31;
  const int ty = threadIdx.x >> 5;

  const float* xb = x + (size_t)b * C * N;
  const float* xpb = xp + (size_t)b * C * N;
  float s = 0.f, s2 = 0.f;
#pragma unroll
  for (int st = 0; st < 12; ++st) {
    const int c = st * 8 + ty;
    const float v = xb[(size_t)c * N + n0 + tx];
    const float u = xpb[(size_t)c * N + n0 + tx];
    t0[c][tx] = v;
    t1[c][tx] = u;
    s += v;
    s2 += v * v;
  }
  red1[ty][tx] = s;
  red2[ty][tx] = s2;
  __syncthreads();

  float* xTb = xT + (size_t)b * N * C;
  float* xpTb = xpT + (size_t)b * N * C;
  const int tid = threadIdx.x;
#pragma unroll
  for (int r = 0; r < 12; ++r) {
    const int f = r * 256 + tid;      // f = nl*96 + c, coalesced
    const int nl = f / 96;
    const int c = f - nl * 96;
    xTb[(size_t)(n0 + nl) * C + c] = t0[c][nl];
    xpTb[(size_t)(n0 + nl) * C + c] = t1[c][nl];
  }
  if (ty == 0) {
    float S = 0.f, S2 = 0.f;
#pragma unroll
    for (int yy = 0; yy < 8; ++yy) {
      S += red1[yy][tx];
      S2 += red2[yy][tx];
    }
    cstat[(size_t)b * N + n0 + tx] = make_float2(S, S2);
  }
}

// ---------------------------------------------------------------------------
// Kernel B: main fused kernel with a HAND-SCHEDULED load pipeline.
// One wave per (b,n); XCD-pinned. Lane = 8g+w; group g owns k={g,g+8,g+16};
// per round each lane covers 12 channels (3 float4 per array).
// All gathers are issued by asm volatile global_load (order locked), and
// consumed behind counted "s_waitcnt vmcnt(N)" + sched_barrier(0) fences.
// Up to 22 loads in flight. Butterfly: DPP quad_perm (xor1,xor2) + one
// ds_swizzle (xor4). Output written directly to out[B,C,N].
// ---------------------------------------------------------------------------
__global__ __launch_bounds__(256) void ssim_main_kernel(
    const float* __restrict__ xT, const float* __restrict__ xpT,
    const float2* __restrict__ cstat, const int* __restrict__ eidx,
    float* __restrict__ out) {
  __shared__ float red[4][C][9];      // [wave][channel][group], pad 9
  const int wave = threadIdx.x >> 6;
  const int lane = threadIdx.x & 63;
  const int b = blockIdx.x & 7;       // XCD pin: batch == blockIdx % 8
  const int tile = blockIdx.x >> 3;
  const int n = tile * 4 + wave;

  // lanes 0..17 -> j_k (edge_index[0]), lanes 18..35 -> i_k (edge_index[1])
  int myidx = 0;
  if (lane < 36) {
    const int s = (lane >= 18) ? 1 : 0;
    const int k = lane - 18 * s;
    myidx = eidx[((size_t)(s * B + b) * N + n) * K + k];
  }

  const float* xb = xT + (size_t)b * N * C;
  const float* xpb = xpT + (size_t)b * N * C;
  const float2* cs = cstat + (size_t)b * N;
  const int g = lane >> 3;
  const int w = lane & 7;

  // per-lane column ids for the 3 rounds (k = r*8+g, clamped)
  int ci0, cj0, ci1, cj1, ci2, cj2;
  {
    int k0 = g, k1 = 8 + g, k2 = 16 + g;
    if (k2 > 17) k2 = 17;             // r=2, g>=2: duplicate (masked later)
    cj0 = __shfl(myidx, k0, 64);
    ci0 = __shfl(myidx, 18 + k0, 64);
    cj1 = __shfl(myidx, k1, 64);
    ci1 = __shfl(myidx, 18 + k1, 64);
    cj2 = __shfl(myidx, k2, 64);
    ci2 = __shfl(myidx, 18 + k2, 64);
  }
  const float mask2 = (g < 2) ? 1.f : 0.f;

  const float* xiA0 = xb + (size_t)ci0 * C + w * 12;
  const float* xjA0 = xb + (size_t)cj0 * C + w * 12;
  const float* piA0 = xpb + (size_t)ci0 * C + w * 12;
  const float* pjA0 = xpb + (size_t)cj0 * C + w * 12;
  const float* xiA1 = xb + (size_t)ci1 * C + w * 12;
  const float* xjA1 = xb + (size_t)cj1 * C + w * 12;
  const float* piA1 = xpb + (size_t)ci1 * C + w * 12;
  const float* pjA1 = xpb + (size_t)cj1 * C + w * 12;
  const float* xiA2 = xb + (size_t)ci2 * C + w * 12;
  const float* xjA2 = xb + (size_t)cj2 * C + w * 12;
  const float* piA2 = xpb + (size_t)ci2 * C + w * 12;
  const float* pjA2 = xpb + (size_t)cj2 * C + w * 12;

  float2 si0, sj0, si1, sj1, si2, sj2;
  float4 xi0a, xi0b, xi0c, xj0a, xj0b, xj0c;
  float4 xi1a, xi1b, xi1c, xj1a, xj1b, xj1c;
  float4 xi2a, xi2b, xi2c, xj2a, xj2b, xj2c;
  float4 pi0a, pi0b, pi0c, pj0a, pj0b, pj0c;
  float4 pi1a, pi1b, pi1c, pj1a, pj1b, pj1c;
  float4 pi2a, pi2b, pi2c, pj2a, pj2b, pj2c;

  // ---- issue A0 (8), A1 (8), P0 (6) --------------------------------------
  GL2(si0, cs + ci0); GL2(sj0, cs + cj0);
  GL4(xi0a, xiA0, 0); GL4(xi0b, xiA0, 16); GL4(xi0c, xiA0, 32);
  GL4(xj0a, xjA0, 0); GL4(xj0b, xjA0, 16); GL4(xj0c, xjA0, 32);
  GL2(si1, cs + ci1); GL2(sj1, cs + cj1);
  GL4(xi1a, xiA1, 0); GL4(xi1b, xiA1, 16); GL4(xi1c, xiA1, 32);
  GL4(xj1a, xjA1, 0); GL4(xj1b, xjA1, 16); GL4(xj1c, xjA1, 32);
  GL4(pi0a, piA0, 0); GL4(pi0b, piA0, 16); GL4(pi0c, piA0, 32);
  GL4(pj0a, pjA0, 0); GL4(pj0b, pjA0, 16); GL4(pj0c, pjA0, 32);

  // ---- wait for A0 (8 newest outstanding: A1(8)+P0(6) = 14) --------------
  VMWAIT(14);
  float p0 = dot4(xi0a, xj0a, 0.f);
  p0 = dot4(xi0b, xj0b, p0);
  p0 = dot4(xi0c, xj0c, p0);
  const float sff0 = sff_of(qsum8(p0), si0, sj0);

  // ---- issue A2 (8) -> queue A1(8)+P0(6)+A2(8) ---------------------------
  GL2(si2, cs + ci2); GL2(sj2, cs + cj2);
  GL4(xi2a, xiA2, 0); GL4(xi2b, xiA2, 16); GL4(xi2c, xiA2, 32);
  GL4(xj2a, xjA2, 0); GL4(xj2b, xjA2, 16); GL4(xj2c, xjA2, 32);

  // ---- wait for A1+P0 (A2(8) still outstanding) --------------------------
  VMWAIT(8);

  float4 acc0 = make_float4(0.f, 0.f, 0.f, 0.f);
  float4 acc1 = make_float4(0.f, 0.f, 0.f, 0.f);
  float4 acc2 = make_float4(0.f, 0.f, 0.f, 0.f);
#define ACCUM4(U, V, ACC, SFF, MSK)                                          \
  ACC.x = fmaf(MSK, U.x + V.x, fmaf((SFF) * (MSK), fabsf(U.x - V.x), ACC.x)); \
  ACC.y = fmaf(MSK, U.y + V.y, fmaf((SFF) * (MSK), fabsf(U.y - V.y), ACC.y)); \
  ACC.z = fmaf(MSK, U.z + V.z, fmaf((SFF) * (MSK), fabsf(U.z - V.z), ACC.z)); \
  ACC.w = fmaf(MSK, U.w + V.w, fmaf((SFF) * (MSK), fabsf(U.w - V.w), ACC.w))

  // accum round 0
  ACCUM4(pi0a, pj0a, acc0, sff0, 1.f);
  ACCUM4(pi0b, pj0b, acc1, sff0, 1.f);
  ACCUM4(pi0c, pj0c, acc2, sff0, 1.f);

  // ---- issue P1 (6) -> queue A2(8)+P1(6) ---------------------------------
  GL4(pi1a, piA1, 0); GL4(pi1b, piA1, 16); GL4(pi1c, piA1, 32);
  GL4(pj1a, pjA1, 0); GL4(pj1b, pjA1, 16); GL4(pj1c, pjA1, 32);

  // dot1/sff1 (A1 data already waited above)
  float p1 = dot4(xi1a, xj1a, 0.f);
  p1 = dot4(xi1b, xj1b, p1);
  p1 = dot4(xi1c, xj1c, p1);
  const float sff1 = sff_of(qsum8(p1), si1, sj1);

  // ---- wait for A2 (P1(6) outstanding), issue P2 (6) ---------------------
  VMWAIT(6);
  GL4(pi2a, piA2, 0); GL4(pi2b, piA2, 16); GL4(pi2c, piA2, 32);
  GL4(pj2a, pjA2, 0); GL4(pj2b, pjA2, 16); GL4(pj2c, pjA2, 32);

  float p2 = dot4(xi2a, xj2a, 0.f);
  p2 = dot4(xi2b, xj2b, p2);
  p2 = dot4(xi2c, xj2c, p2);
  const float sff2 = sff_of(qsum8(p2), si2, sj2);

  // ---- wait for P1 (P2(6) outstanding), accum round 1 --------------------
  VMWAIT(6);
  ACCUM4(pi1a, pj1a, acc0, sff1, 1.f);
  ACCUM4(pi1b, pj1b, acc1, sff1, 1.f);
  ACCUM4(pi1c, pj1c, acc2, sff1, 1.f);

  // ---- wait for P2, accum round 2 (masked for duplicate k) ---------------
  VMWAIT(0);
  ACCUM4(pi2a, pj2a, acc0, sff2, mask2);
  ACCUM4(pi2b, pj2b, acc1, sff2, mask2);
  ACCUM4(pi2c, pj2c, acc2, sff2, mask2);
#undef ACCUM4

  // ---- cross-group reduction (wave-local LDS) ----------------------------
  red[wave][w * 12 + 0][g] = acc0.x;
  red[wave][w * 12 + 1][g] = acc0.y;
  red[wave][w * 12 + 2][g] = acc0.z;
  red[wave][w * 12 + 3][g] = acc0.w;
  red[wave][w * 12 + 4][g] = acc1.x;
  red[wave][w * 12 + 5][g] = acc1.y;
  red[wave][w * 12 + 6][g] = acc1.z;
  red[wave][w * 12 + 7][g] = acc1.w;
  red[wave][w * 12 + 8][g] = acc2.x;
  red[wave][w * 12 + 9][g] = acc2.y;
  red[wave][w * 12 + 10][g] = acc2.z;
  red[wave][w * 12 + 11][g] = acc2.w;

  float s1 = 0.f;
#pragma unroll
  for (int gg = 0; gg < 8; ++gg) s1 += red[wave][lane][gg];
  out[((size_t)b * C + lane) * N + n] = s1;
  if (lane < 32) {
    float s2 = 0.f;
#pragma unroll
    for (int gg = 0; gg < 8; ++gg) s2 += red[wave][lane + 64][gg];
    out[((size_t)b * C + lane + 64) * N + n] = s2;
  }
}

// ---------------------------------------------------------------------------
// Fallback (only used if ws_size is too small): slow but correct.
// ---------------------------------------------------------------------------
__global__ void fallback_kernel(const float* __restrict__ x,
                                const float* __restrict__ xp,
                                const int* __restrict__ e,
                                float* __restrict__ out) {
  const int gn = blockIdx.x * 64 + threadIdx.x;
  if (gn >= B * N) return;
  const int b = gn / N;
  const int n = gn - b * N;
  const float* xb = x + (size_t)b * C * N;
  const float* xpb = xp + (size_t)b * C * N;
  int ii[K], jj[K];
  float sff[K];
#pragma unroll
  for (int k = 0; k < K; ++k) {
    jj[k] = e[((size_t)(0 * B + b) * N + n) * K + k];
    ii[k] = e[((size_t)(1 * B + b) * N + n) * K + k];
    float si = 0, sj = 0, sii = 0, sjj = 0, sij = 0;
    for (int c = 0; c < C; ++c) {
      const float a = xb[(size_t)c * N + ii[k]];
      const float q = xb[(size_t)c * N + jj[k]];
      si += a; sj += q; sii += a * a; sjj += q * q; sij += a * q;
    }
    const float mi = si * (1.f / C), mj = sj * (1.f / C);
    const float vi = sii * (1.f / C) - mi * mi;
    const float vj = sjj * (1.f / C) - mj * mj;
    const float cov = sij * (1.f / C) - mi * mj;
    const float S1 = (2.f * mi * mj + C1c) / (mi * mi + mj * mj + C1c);
    const float S2 = (2.f * cov + C2c) / (vi + vj + C2c);
    sff[k] = 1.f - S1 * S2;
  }
  for (int c = 0; c < C; ++c) {
    float acc = 0.f;
#pragma unroll
    for (int k = 0; k < K; ++k) {
      const float a = xpb[(size_t)c * N + ii[k]];
      const float q = xpb[(size_t)c * N + jj[k]];
      acc += a + q + fabsf(a - q) * sff[k];
    }
    out[((size_t)b * C + c) * N + n] = acc;
  }
}

// ---------------------------------------------------------------------------
extern "C" void kernel_launch(void* const* d_in, const int* in_sizes, int n_in,
                              void* d_out, int out_size, void* d_ws, size_t ws_size,
                              hipStream_t stream) {
  const float* x = (const float*)d_in[0];
  const float* xp = (const float*)d_in[1];
  const int* e = (const int*)d_in[2];
  float* out = (float*)d_out;

  const size_t nBNC = (size_t)B * N * C;
  const size_t nBN = (size_t)B * N;
  const size_t need = 2 * nBNC * sizeof(float) + nBN * sizeof(float2);

  if (ws_size >= need) {
    float* ws = (float*)d_ws;
    float* xT = ws;
    float* xpT = xT + nBNC;
    float2* cstat = (float2*)(xpT + nBNC);

    fusedT_kernel<<<8 * (N / 32), 256, 0, stream>>>(x, xp, xT, xpT, cstat);
    ssim_main_kernel<<<(B * N) / 4, 256, 0, stream>>>(xT, xpT, cstat, e, out);
  } else {
    fallback_kernel<<<(B * N + 63) / 64, 64, 0, stream>>>(x, xp, e, out);
  }
}

// Round 10
// 53.634 us; speedup vs baseline: 1.2658x; 1.0071x over previous
//
#include <hip/hip_runtime.h>
#include <cstdint>
#include <cstddef>

// Problem constants (from reference)
constexpr int B = 8, C = 96, N = 3136, K = 18;
constexpr float C1c = 1e-6f, C2c = 1e-6f;

// ---------------------------------------------------------------------------
// Kernel A (fused): transpose x,xp [B,C,N]->[B,N,C] AND per-column channel
// sums of x (cstat = {Σx, Σx²}). XCD-pinned: blockIdx&7 == batch.
// ---------------------------------------------------------------------------
__global__ __launch_bounds__(256) void fusedT_kernel(
    const float* __restrict__ x, const float* __restrict__ xp,
    float* __restrict__ xT, float* __restrict__ xpT,
    float2* __restrict__ cstat) {
  __shared__ float t0[C][33];
  __shared__ float t1[C][33];
  __shared__ float red1[8][33];
  __shared__ float red2[8][33];
  const int bid = blockIdx.x;
  const int b = bid & 7;              // XCD pin
  const int n0 = (bid >> 3) * 32;
  const int tx = threadIdx.x & 31;
  const int ty = threadIdx.x >> 5;

  const float* xb = x + (size_t)b * C * N;
  const float* xpb = xp + (size_t)b * C * N;
  float s = 0.f, s2 = 0.f;
#pragma unroll
  for (int st = 0; st < 12; ++st) {
    const int c = st * 8 + ty;
    const float v = xb[(size_t)c * N + n0 + tx];
    const float u = xpb[(size_t)c * N + n0 + tx];
    t0[c][tx] = v;
    t1[c][tx] = u;
    s += v;
    s2 += v * v;
  }
  red1[ty][tx] = s;
  red2[ty][tx] = s2;
  __syncthreads();

  float* xTb = xT + (size_t)b * N * C;
  float* xpTb = xpT + (size_t)b * N * C;
  const int tid = threadIdx.x;
#pragma unroll
  for (int r = 0; r < 12; ++r) {
    const int f = r * 256 + tid;      // f = nl*96 + c, coalesced
    const int nl = f / 96;
    const int c = f - nl * 96;
    xTb[(size_t)(n0 + nl) * C + c] = t0[c][nl];
    xpTb[(size_t)(n0 + nl) * C + c] = t1[c][nl];
  }
  if (ty == 0) {
    float S = 0.f, S2 = 0.f;
#pragma unroll
    for (int yy = 0; yy < 8; ++yy) {
      S += red1[yy][tx];
      S2 += red2[yy][tx];
    }
    cstat[(size_t)b * N + n0 + tx] = make_float2(S, S2);
  }
}

// ---------------------------------------------------------------------------
// Kernel B: main fused kernel, single-phase, SECTOR-CLEAN lane mapping.
// One wave per (b,n); XCD-pinned. Lane = 8g+w; group g owns k={g,g+8,g+16}.
// Lane w owns channels {4w..4w+3} U {32+4w..} U {64+4w..}: each float4 load
// instruction has its 8 group-lanes 16B-CONTIGUOUS (128B per group, 2
// sectors, zero cross-instruction sector overlap) — vs the old 48B-stride
// layout that touched every sector 3x. Per round: load x_i, x_j, xp_i, xp_j
// (12 float4 + 2 stat float2, one basic block), dot via 3-level in-group
// butterfly, group-parallel sff consumed in place, fused xp accumulation.
// Cross-group reduction via LDS [96][9]; direct strided write to out[B,C,N].
// ---------------------------------------------------------------------------
__global__ __launch_bounds__(256, 4) void ssim_main_kernel(
    const float* __restrict__ xT, const float* __restrict__ xpT,
    const float2* __restrict__ cstat, const int* __restrict__ eidx,
    float* __restrict__ out) {
  __shared__ float red[4][C][9];      // [wave][channel][group], pad 9
  const int wave = threadIdx.x >> 6;
  const int lane = threadIdx.x & 63;
  const int b = blockIdx.x & 7;       // XCD pin: batch == blockIdx % 8
  const int tile = blockIdx.x >> 3;
  const int n = tile * 4 + wave;

  // lanes 0..17 -> j_k (edge_index[0]), lanes 18..35 -> i_k (edge_index[1])
  int myidx = 0;
  if (lane < 36) {
    const int s = (lane >= 18) ? 1 : 0;
    const int k = lane - 18 * s;
    myidx = eidx[((size_t)(s * B + b) * N + n) * K + k];
  }

  const float* xb = xT + (size_t)b * N * C;
  const float* xpb = xpT + (size_t)b * N * C;
  const float2* cs = cstat + (size_t)b * N;
  const int g = lane >> 3;
  const int w = lane & 7;

  float acc[12];
#pragma unroll
  for (int d = 0; d < 12; ++d) acc[d] = 0.f;

#pragma unroll
  for (int r = 0; r < 3; ++r) {
    int k = r * 8 + g;
    float mask = 1.f;
    if (k > K - 1) {                  // r=2, g>=2: duplicate k, masked out
      k = K - 1;
      mask = 0.f;
    }
    const int cj = __shfl(myidx, k, 64);
    const int ci = __shfl(myidx, 18 + k, 64);
    // lane w: floats {4w, 32+4w, 64+4w} -> 16B-contiguous lanes per instr
    const float* xi = xb + (size_t)ci * C + 4 * w;
    const float* xj = xb + (size_t)cj * C + 4 * w;
    const float* pi = xpb + (size_t)ci * C + 4 * w;
    const float* pj = xpb + (size_t)cj * C + 4 * w;
    const float4 a0 = *(const float4*)(xi);
    const float4 a1 = *(const float4*)(xi + 32);
    const float4 a2 = *(const float4*)(xi + 64);
    const float4 q0 = *(const float4*)(xj);
    const float4 q1 = *(const float4*)(xj + 32);
    const float4 q2 = *(const float4*)(xj + 64);
    const float4 u0 = *(const float4*)(pi);
    const float4 u1 = *(const float4*)(pi + 32);
    const float4 u2 = *(const float4*)(pi + 64);
    const float4 v0 = *(const float4*)(pj);
    const float4 v1 = *(const float4*)(pj + 32);
    const float4 v2 = *(const float4*)(pj + 64);
    const float2 si = cs[ci];
    const float2 sj = cs[cj];

    float p = a0.x * q0.x + a0.y * q0.y + a0.z * q0.z + a0.w * q0.w;
    p += a1.x * q1.x + a1.y * q1.y + a1.z * q1.z + a1.w * q1.w;
    p += a2.x * q2.x + a2.y * q2.y + a2.z * q2.z + a2.w * q2.w;
    p += __shfl_xor(p, 1, 64);        // in-group butterfly (8 lanes)
    p += __shfl_xor(p, 2, 64);
    p += __shfl_xor(p, 4, 64);

    const float mi = si.x * (1.0f / C), mj = sj.x * (1.0f / C);
    const float vi = si.y * (1.0f / C) - mi * mi;
    const float vj = sj.y * (1.0f / C) - mj * mj;
    const float cov = p * (1.0f / C) - mi * mj;
    const float S1 =
        (2.f * mi * mj + C1c) * __builtin_amdgcn_rcpf(mi * mi + mj * mj + C1c);
    const float S2 = (2.f * cov + C2c) * __builtin_amdgcn_rcpf(vi + vj + C2c);
    const float sff = 1.f - S1 * S2;
    const float sm = sff * mask;

    auto accum4 = [&](const float4& u, const float4& v, int base) {
      acc[base + 0] =
          fmaf(mask, u.x + v.x, fmaf(sm, fabsf(u.x - v.x), acc[base + 0]));
      acc[base + 1] =
          fmaf(mask, u.y + v.y, fmaf(sm, fabsf(u.y - v.y), acc[base + 1]));
      acc[base + 2] =
          fmaf(mask, u.z + v.z, fmaf(sm, fabsf(u.z - v.z), acc[base + 2]));
      acc[base + 3] =
          fmaf(mask, u.w + v.w, fmaf(sm, fabsf(u.w - v.w), acc[base + 3]));
    };
    accum4(u0, v0, 0);
    accum4(u1, v1, 4);
    accum4(u2, v2, 8);
  }

  // ---- cross-group reduction (wave-local LDS, no barrier needed) ---------
  // acc[t*4+d] is channel c = t*32 + 4w + d
#pragma unroll
  for (int t = 0; t < 3; ++t) {
#pragma unroll
    for (int d = 0; d < 4; ++d) {
      red[wave][t * 32 + 4 * w + d][g] = acc[t * 4 + d];
    }
  }

  float s1 = 0.f;
#pragma unroll
  for (int gg = 0; gg < 8; ++gg) s1 += red[wave][lane][gg];
  out[((size_t)b * C + lane) * N + n] = s1;
  if (lane < 32) {
    float s2 = 0.f;
#pragma unroll
    for (int gg = 0; gg < 8; ++gg) s2 += red[wave][lane + 64][gg];
    out[((size_t)b * C + lane + 64) * N + n] = s2;
  }
}

// ---------------------------------------------------------------------------
// Fallback (only used if ws_size is too small): slow but correct.
// ---------------------------------------------------------------------------
__global__ void fallback_kernel(const float* __restrict__ x,
                                const float* __restrict__ xp,
                                const int* __restrict__ e,
                                float* __restrict__ out) {
  const int gn = blockIdx.x * 64 + threadIdx.x;
  if (gn >= B * N) return;
  const int b = gn / N;
  const int n = gn - b * N;
  const float* xb = x + (size_t)b * C * N;
  const float* xpb = xp + (size_t)b * C * N;
  int ii[K], jj[K];
  float sff[K];
#pragma unroll
  for (int k = 0; k < K; ++k) {
    jj[k] = e[((size_t)(0 * B + b) * N + n) * K + k];
    ii[k] = e[((size_t)(1 * B + b) * N + n) * K + k];
    float si = 0, sj = 0, sii = 0, sjj = 0, sij = 0;
    for (int c = 0; c < C; ++c) {
      const float a = xb[(size_t)c * N + ii[k]];
      const float q = xb[(size_t)c * N + jj[k]];
      si += a; sj += q; sii += a * a; sjj += q * q; sij += a * q;
    }
    const float mi = si * (1.f / C), mj = sj * (1.f / C);
    const float vi = sii * (1.f / C) - mi * mi;
    const float vj = sjj * (1.f / C) - mj * mj;
    const float cov = sij * (1.f / C) - mi * mj;
    const float S1 = (2.f * mi * mj + C1c) / (mi * mi + mj * mj + C1c);
    const float S2 = (2.f * cov + C2c) / (vi + vj + C2c);
    sff[k] = 1.f - S1 * S2;
  }
  for (int c = 0; c < C; ++c) {
    float acc = 0.f;
#pragma unroll
    for (int k = 0; k < K; ++k) {
      const float a = xpb[(size_t)c * N + ii[k]];
      const float q = xpb[(size_t)c * N + jj[k]];
      acc += a + q + fabsf(a - q) * sff[k];
    }
    out[((size_t)b * C + c) * N + n] = acc;
  }
}

// ---------------------------------------------------------------------------
extern "C" void kernel_launch(void* const* d_in, const int* in_sizes, int n_in,
                              void* d_out, int out_size, void* d_ws, size_t ws_size,
                              hipStream_t stream) {
  const float* x = (const float*)d_in[0];
  const float* xp = (const float*)d_in[1];
  const int* e = (const int*)d_in[2];
  float* out = (float*)d_out;

  const size_t nBNC = (size_t)B * N * C;
  const size_t nBN = (size_t)B * N;
  const size_t need = 2 * nBNC * sizeof(float) + nBN * sizeof(float2);

  if (ws_size >= need) {
    float* ws = (float*)d_ws;
    float* xT = ws;
    float* xpT = xT + nBNC;
    float2* cstat = (float2*)(xpT + nBNC);

    fusedT_kernel<<<8 * (N / 32), 256, 0, stream>>>(x, xp, xT, xpT, cstat);
    ssim_main_kernel<<<(B * N) / 4, 256, 0, stream>>>(xT, xpT, cstat, e, out);
  } else {
    fallback_kernel<<<(B * N + 63) / 64, 64, 0, stream>>>(x, xp, e, out);
  }
}

// Round 11
// 41.885 us; speedup vs baseline: 1.6209x; 1.2805x over previous
//
#include <hip/hip_runtime.h>
#include <cstdint>
#include <cstddef>

// Problem constants (from reference)
constexpr int B = 8, C = 96, N = 3136, K = 18;
constexpr float C1c = 1e-6f, C2c = 1e-6f;

typedef unsigned int uint32;
typedef unsigned short ushort16;

__device__ inline float readlane_f(float v, int l) {
  return __builtin_bit_cast(float,
                            __builtin_amdgcn_readlane(__builtin_bit_cast(int, v), l));
}

// f32 -> bf16 with round-to-nearest-even
__device__ inline ushort16 f2bf(float f) {
  uint32 u = __builtin_bit_cast(uint32, f);
  return (ushort16)((u + 0x7FFFu + ((u >> 16) & 1u)) >> 16);
}
// bf16 pair (packed in a uint) -> f32
__device__ inline float bflo(uint32 u) {
  return __builtin_bit_cast(float, u << 16);
}
__device__ inline float bfhi(uint32 u) {
  return __builtin_bit_cast(float, u & 0xFFFF0000u);
}
// acc += dot of the 2 bf16 pairs in a,b
__device__ inline float dot2(uint32 a, uint32 b, float acc) {
  return fmaf(bflo(a), bflo(b), fmaf(bfhi(a), bfhi(b), acc));
}

// ---------------------------------------------------------------------------
// Kernel A (fused): transpose x,xp [B,C,N] -> bf16 [B,N,C] AND per-column
// channel sums of x in f32 (cstat = {Σx, Σx²}). XCD-pinned: blockIdx&7 == b.
// ---------------------------------------------------------------------------
__global__ __launch_bounds__(256) void fusedT_kernel(
    const float* __restrict__ x, const float* __restrict__ xp,
    ushort16* __restrict__ xT, ushort16* __restrict__ xpT,
    float2* __restrict__ cstat) {
  __shared__ float t0[C][33];
  __shared__ float t1[C][33];
  __shared__ float red1[8][33];
  __shared__ float red2[8][33];
  const int bid = blockIdx.x;
  const int b = bid & 7;              // XCD pin
  const int n0 = (bid >> 3) * 32;
  const int tx = threadIdx.x & 31;
  const int ty = threadIdx.x >> 5;

  const float* xb = x + (size_t)b * C * N;
  const float* xpb = xp + (size_t)b * C * N;
  float s = 0.f, s2 = 0.f;
#pragma unroll
  for (int st = 0; st < 12; ++st) {
    const int c = st * 8 + ty;
    const float v = xb[(size_t)c * N + n0 + tx];
    const float u = xpb[(size_t)c * N + n0 + tx];
    t0[c][tx] = v;
    t1[c][tx] = u;
    s += v;
    s2 += v * v;
  }
  red1[ty][tx] = s;
  red2[ty][tx] = s2;
  __syncthreads();

  ushort16* xTb = xT + (size_t)b * N * C;
  ushort16* xpTb = xpT + (size_t)b * N * C;
  const int tid = threadIdx.x;
#pragma unroll
  for (int r = 0; r < 12; ++r) {
    const int f = r * 256 + tid;      // f = nl*96 + c, coalesced
    const int nl = f / 96;
    const int c = f - nl * 96;
    xTb[(size_t)(n0 + nl) * C + c] = f2bf(t0[c][nl]);
    xpTb[(size_t)(n0 + nl) * C + c] = f2bf(t1[c][nl]);
  }
  if (ty == 0) {
    float S = 0.f, S2 = 0.f;
#pragma unroll
    for (int yy = 0; yy < 8; ++yy) {
      S += red1[yy][tx];
      S2 += red2[yy][tx];
    }
    cstat[(size_t)b * N + n0 + tx] = make_float2(S, S2);
  }
}

// ---------------------------------------------------------------------------
// Kernel B: main fused kernel, R4 two-phase structure + bf16 gather payloads.
// One wave per (b,n); XCD-pinned (blockIdx&7 = b). No LDS.
//   Phase 1: group-parallel dots — lane = 8g+w; group g owns k={g,g+8,g+16};
//     lane covers channels {12w..12w+11} via 3x uint2 (8B) bf16 loads per
//     column; 3-level in-group butterfly; group-parallel sff.
//   Broadcast: 36 column indices + 18 sff values -> SGPRs via readlane.
//   Phase 2: lane l<48 owns channels {2l,2l+1}; each xp column is ONE 4B
//     load (192B contiguous per instruction); fused accumulate; direct
//     strided write to out[B,C,N] (absorbed by XCD-local L2).
// ---------------------------------------------------------------------------
__global__ __launch_bounds__(256, 4) void ssim_main_kernel(
    const ushort16* __restrict__ xT, const ushort16* __restrict__ xpT,
    const float2* __restrict__ cstat, const int* __restrict__ eidx,
    float* __restrict__ out) {
  const int wave = threadIdx.x >> 6;
  const int lane = threadIdx.x & 63;
  const int b = blockIdx.x & 7;       // XCD pin: batch == blockIdx % 8
  const int tile = blockIdx.x >> 3;
  const int n = tile * 4 + wave;

  // lanes 0..17 -> j_k (edge_index[0]), lanes 18..35 -> i_k (edge_index[1])
  int myidx = 0;
  if (lane < 36) {
    const int s = (lane >= 18) ? 1 : 0;
    const int k = lane - 18 * s;
    myidx = eidx[((size_t)(s * B + b) * N + n) * K + k];
  }

  const ushort16* xb = xT + (size_t)b * N * C;
  const float2* cs = cstat + (size_t)b * N;
  const int g = lane >> 3;
  const int w = lane & 7;

  // ---- Phase 1: 3 group-parallel rounds ----------------------------------
  float sffr[3];
#pragma unroll
  for (int r = 0; r < 3; ++r) {
    int k = r * 8 + g;
    if (k > K - 1) k = K - 1;         // r=2, g>=2: redundant k=17 (unused)
    const int cj = __shfl(myidx, k, 64);
    const int ci = __shfl(myidx, 18 + k, 64);
    const uint2* xi = (const uint2*)(xb + (size_t)ci * C + 12 * w);
    const uint2* xj = (const uint2*)(xb + (size_t)cj * C + 12 * w);
    const uint2 a0 = xi[0], a1 = xi[1], a2 = xi[2];
    const uint2 q0 = xj[0], q1 = xj[1], q2 = xj[2];
    const float2 si = cs[ci];
    const float2 sj = cs[cj];

    float p = dot2(a0.x, q0.x, 0.f);
    p = dot2(a0.y, q0.y, p);
    p = dot2(a1.x, q1.x, p);
    p = dot2(a1.y, q1.y, p);
    p = dot2(a2.x, q2.x, p);
    p = dot2(a2.y, q2.y, p);
    p += __shfl_xor(p, 1, 64);        // in-group butterfly (8 lanes)
    p += __shfl_xor(p, 2, 64);
    p += __shfl_xor(p, 4, 64);

    const float mi = si.x * (1.0f / C), mj = sj.x * (1.0f / C);
    const float vi = si.y * (1.0f / C) - mi * mi;
    const float vj = sj.y * (1.0f / C) - mj * mj;
    const float cov = p * (1.0f / C) - mi * mj;
    const float S1 =
        (2.f * mi * mj + C1c) * __builtin_amdgcn_rcpf(mi * mi + mj * mj + C1c);
    const float S2 = (2.f * cov + C2c) * __builtin_amdgcn_rcpf(vi + vj + C2c);
    sffr[r] = 1.f - S1 * S2;
  }

  // ---- Broadcast to wave-uniform SGPRs -----------------------------------
  float sk[K];
#pragma unroll
  for (int k = 0; k < K; ++k) sk[k] = readlane_f(sffr[k >> 3], (k & 7) * 8);
  int jjs[K], jis[K];
#pragma unroll
  for (int k = 0; k < K; ++k) {
    jjs[k] = __builtin_amdgcn_readlane(myidx, k);
    jis[k] = __builtin_amdgcn_readlane(myidx, 18 + k);
  }

  // ---- Phase 2: xp accumulation, one 4B load per column ------------------
  const uint32* xpb32 = (const uint32*)(xpT + (size_t)b * N * C);
  const int l = (lane < 48) ? lane : 47;
  float tx = 0.f, ty = 0.f, ax = 0.f, ay = 0.f;
#pragma unroll
  for (int k = 0; k < K; ++k) {
    const uint32 a = xpb32[(size_t)jis[k] * 48 + l];
    const uint32 q = xpb32[(size_t)jjs[k] * 48 + l];
    const float a0 = bflo(a), a1 = bfhi(a);
    const float q0 = bflo(q), q1 = bfhi(q);
    tx += a0 + q0;
    ty += a1 + q1;
    ax = fmaf(fabsf(a0 - q0), sk[k], ax);
    ay = fmaf(fabsf(a1 - q1), sk[k], ay);
  }

  if (lane < 48) {
    float* ob = out + ((size_t)b * C + 2 * lane) * N + n;
    ob[0] = tx + ax;
    ob[N] = ty + ay;
  }
}

// ---------------------------------------------------------------------------
// Fallback (only used if ws_size is too small): slow but correct (f32).
// ---------------------------------------------------------------------------
__global__ void fallback_kernel(const float* __restrict__ x,
                                const float* __restrict__ xp,
                                const int* __restrict__ e,
                                float* __restrict__ out) {
  const int gn = blockIdx.x * 64 + threadIdx.x;
  if (gn >= B * N) return;
  const int b = gn / N;
  const int n = gn - b * N;
  const float* xb = x + (size_t)b * C * N;
  const float* xpb = xp + (size_t)b * C * N;
  int ii[K], jj[K];
  float sff[K];
#pragma unroll
  for (int k = 0; k < K; ++k) {
    jj[k] = e[((size_t)(0 * B + b) * N + n) * K + k];
    ii[k] = e[((size_t)(1 * B + b) * N + n) * K + k];
    float si = 0, sj = 0, sii = 0, sjj = 0, sij = 0;
    for (int c = 0; c < C; ++c) {
      const float a = xb[(size_t)c * N + ii[k]];
      const float q = xb[(size_t)c * N + jj[k]];
      si += a; sj += q; sii += a * a; sjj += q * q; sij += a * q;
    }
    const float mi = si * (1.f / C), mj = sj * (1.f / C);
    const float vi = sii * (1.f / C) - mi * mi;
    const float vj = sjj * (1.f / C) - mj * mj;
    const float cov = sij * (1.f / C) - mi * mj;
    const float S1 = (2.f * mi * mj + C1c) / (mi * mi + mj * mj + C1c);
    const float S2 = (2.f * cov + C2c) / (vi + vj + C2c);
    sff[k] = 1.f - S1 * S2;
  }
  for (int c = 0; c < C; ++c) {
    float acc = 0.f;
#pragma unroll
    for (int k = 0; k < K; ++k) {
      const float a = xpb[(size_t)c * N + ii[k]];
      const float q = xpb[(size_t)c * N + jj[k]];
      acc += a + q + fabsf(a - q) * sff[k];
    }
    out[((size_t)b * C + c) * N + n] = acc;
  }
}

// ---------------------------------------------------------------------------
extern "C" void kernel_launch(void* const* d_in, const int* in_sizes, int n_in,
                              void* d_out, int out_size, void* d_ws, size_t ws_size,
                              hipStream_t stream) {
  const float* x = (const float*)d_in[0];
  const float* xp = (const float*)d_in[1];
  const int* e = (const int*)d_in[2];
  float* out = (float*)d_out;

  const size_t nBNC = (size_t)B * N * C;
  const size_t nBN = (size_t)B * N;
  const size_t need = 2 * nBNC * sizeof(ushort16) + nBN * sizeof(float2);

  if (ws_size >= need) {
    ushort16* xT = (ushort16*)d_ws;
    ushort16* xpT = xT + nBNC;
    float2* cstat = (float2*)(xpT + nBNC);

    fusedT_kernel<<<8 * (N / 32), 256, 0, stream>>>(x, xp, xT, xpT, cstat);
    ssim_main_kernel<<<(B * N) / 4, 256, 0, stream>>>(xT, xpT, cstat, e, out);
  } else {
    fallback_kernel<<<(B * N + 63) / 64, 64, 0, stream>>>(x, xp, e, out);
  }
}

// Round 12
// 36.432 us; speedup vs baseline: 1.8635x; 1.1497x over previous
//
#include <hip/hip_runtime.h>
#include <cstdint>
#include <cstddef>

// Problem constants (from reference)
constexpr int B = 8, C = 96, N = 3136, K = 18;
constexpr float C1c = 1e-6f, C2c = 1e-6f;

typedef unsigned int uint32;
typedef unsigned short ushort16;
typedef _Float16 h2 __attribute__((ext_vector_type(2)));

__device__ inline float readlane_f(float v, int l) {
  return __builtin_bit_cast(float,
                            __builtin_amdgcn_readlane(__builtin_bit_cast(int, v), l));
}

// f32 -> f16 (RNE) as raw ushort
__device__ inline ushort16 f2h(float f) {
  return __builtin_bit_cast(ushort16, (_Float16)f);
}
__device__ inline h2 u2h2(uint32 u) { return __builtin_bit_cast(h2, u); }
__device__ inline h2 habs2(h2 v) {
  return __builtin_bit_cast(h2, __builtin_bit_cast(uint32, v) & 0x7FFF7FFFu);
}
__device__ inline float2 h22f2(h2 v) {
  return make_float2((float)v.x, (float)v.y);
}

// ---------------------------------------------------------------------------
// Kernel A (fused): transpose x,xp [B,C,N] -> f16 [B,N,C] AND per-column
// channel sums of x in f32 (cstat = {Σx, Σx²}). XCD-pinned: blockIdx&7 == b.
// ---------------------------------------------------------------------------
__global__ __launch_bounds__(256) void fusedT_kernel(
    const float* __restrict__ x, const float* __restrict__ xp,
    ushort16* __restrict__ xT, ushort16* __restrict__ xpT,
    float2* __restrict__ cstat) {
  __shared__ float t0[C][33];
  __shared__ float t1[C][33];
  __shared__ float red1[8][33];
  __shared__ float red2[8][33];
  const int bid = blockIdx.x;
  const int b = bid & 7;              // XCD pin
  const int n0 = (bid >> 3) * 32;
  const int tx = threadIdx.x & 31;
  const int ty = threadIdx.x >> 5;

  const float* xb = x + (size_t)b * C * N;
  const float* xpb = xp + (size_t)b * C * N;
  float s = 0.f, s2 = 0.f;
#pragma unroll
  for (int st = 0; st < 12; ++st) {
    const int c = st * 8 + ty;
    const float v = xb[(size_t)c * N + n0 + tx];
    const float u = xpb[(size_t)c * N + n0 + tx];
    t0[c][tx] = v;
    t1[c][tx] = u;
    s += v;
    s2 += v * v;
  }
  red1[ty][tx] = s;
  red2[ty][tx] = s2;
  __syncthreads();

  ushort16* xTb = xT + (size_t)b * N * C;
  ushort16* xpTb = xpT + (size_t)b * N * C;
  const int tid = threadIdx.x;
#pragma unroll
  for (int r = 0; r < 12; ++r) {
    const int f = r * 256 + tid;      // f = nl*96 + c, coalesced
    const int nl = f / 96;
    const int c = f - nl * 96;
    xTb[(size_t)(n0 + nl) * C + c] = f2h(t0[c][nl]);
    xpTb[(size_t)(n0 + nl) * C + c] = f2h(t1[c][nl]);
  }
  if (ty == 0) {
    float S = 0.f, S2 = 0.f;
#pragma unroll
    for (int yy = 0; yy < 8; ++yy) {
      S += red1[yy][tx];
      S2 += red2[yy][tx];
    }
    cstat[(size_t)b * N + n0 + tx] = make_float2(S, S2);
  }
}

// ---------------------------------------------------------------------------
// Kernel B: main fused kernel, two-phase (R4/R11 structure) + f16 payloads.
// One wave per (b,n); XCD-pinned (blockIdx&7 = b).
//   Phase 1: group-parallel dots — lane = 8g+w; group g owns k={g,g+8,g+16};
//     lane covers channels {12w..12w+11} via 3x uint2 (8B) f16 loads per
//     column; dot via 6x v_dot2_f32_f16; 3-level in-group butterfly;
//     group-parallel sff.
//   Broadcast: 36 column indices + 18 sff values -> SGPRs via readlane.
//   Phase 2: lane l<48 owns channels {2l,2l+1}; each xp column is ONE 4B
//     (half2) load; packed v_pk math with 4 alternating f16 partial
//     accumulators (accuracy), f32 combine at the end.
//   Output: block stages 4x96 results in LDS, writes out[B,C,N] with 4
//     consecutive n per 16B segment (4x fewer store segments).
// ---------------------------------------------------------------------------
__global__ __launch_bounds__(256, 4) void ssim_main_kernel(
    const ushort16* __restrict__ xT, const ushort16* __restrict__ xpT,
    const float2* __restrict__ cstat, const int* __restrict__ eidx,
    float* __restrict__ out) {
  __shared__ float ored[4][100];      // [wave][2*48 results], pad 100
  const int wave = threadIdx.x >> 6;
  const int lane = threadIdx.x & 63;
  const int b = blockIdx.x & 7;       // XCD pin: batch == blockIdx % 8
  const int tile = blockIdx.x >> 3;
  const int n = tile * 4 + wave;

  // lanes 0..17 -> j_k (edge_index[0]), lanes 18..35 -> i_k (edge_index[1])
  int myidx = 0;
  if (lane < 36) {
    const int s = (lane >= 18) ? 1 : 0;
    const int k = lane - 18 * s;
    myidx = eidx[((size_t)(s * B + b) * N + n) * K + k];
  }

  const ushort16* xb = xT + (size_t)b * N * C;
  const float2* cs = cstat + (size_t)b * N;
  const int g = lane >> 3;
  const int w = lane & 7;

  // ---- Phase 1: 3 group-parallel rounds ----------------------------------
  float sffr[3];
#pragma unroll
  for (int r = 0; r < 3; ++r) {
    int k = r * 8 + g;
    if (k > K - 1) k = K - 1;         // r=2, g>=2: redundant k=17 (unused)
    const int cj = __shfl(myidx, k, 64);
    const int ci = __shfl(myidx, 18 + k, 64);
    const uint2* xi = (const uint2*)(xb + (size_t)ci * C + 12 * w);
    const uint2* xj = (const uint2*)(xb + (size_t)cj * C + 12 * w);
    const uint2 a0 = xi[0], a1 = xi[1], a2 = xi[2];
    const uint2 q0 = xj[0], q1 = xj[1], q2 = xj[2];
    const float2 si = cs[ci];
    const float2 sj = cs[cj];

    float p = __builtin_amdgcn_fdot2(u2h2(a0.x), u2h2(q0.x), 0.f, false);
    p = __builtin_amdgcn_fdot2(u2h2(a0.y), u2h2(q0.y), p, false);
    p = __builtin_amdgcn_fdot2(u2h2(a1.x), u2h2(q1.x), p, false);
    p = __builtin_amdgcn_fdot2(u2h2(a1.y), u2h2(q1.y), p, false);
    p = __builtin_amdgcn_fdot2(u2h2(a2.x), u2h2(q2.x), p, false);
    p = __builtin_amdgcn_fdot2(u2h2(a2.y), u2h2(q2.y), p, false);
    p += __shfl_xor(p, 1, 64);        // in-group butterfly (8 lanes)
    p += __shfl_xor(p, 2, 64);
    p += __shfl_xor(p, 4, 64);

    const float mi = si.x * (1.0f / C), mj = sj.x * (1.0f / C);
    const float vi = si.y * (1.0f / C) - mi * mi;
    const float vj = sj.y * (1.0f / C) - mj * mj;
    const float cov = p * (1.0f / C) - mi * mj;
    const float S1 =
        (2.f * mi * mj + C1c) * __builtin_amdgcn_rcpf(mi * mi + mj * mj + C1c);
    const float S2 = (2.f * cov + C2c) * __builtin_amdgcn_rcpf(vi + vj + C2c);
    sffr[r] = 1.f - S1 * S2;
  }

  // ---- Broadcast to wave-uniform SGPRs -----------------------------------
  int jjs[K], jis[K];
#pragma unroll
  for (int k = 0; k < K; ++k) {
    jjs[k] = __builtin_amdgcn_readlane(myidx, k);
    jis[k] = __builtin_amdgcn_readlane(myidx, 18 + k);
  }

  // ---- Phase 2: packed f16 xp accumulation -------------------------------
  const uint32* xpb32 = (const uint32*)(xpT + (size_t)b * N * C);
  const int l = (lane < 48) ? lane : 47;
  h2 accT[4] = {h2{0, 0}, h2{0, 0}, h2{0, 0}, h2{0, 0}};
  h2 accX[4] = {h2{0, 0}, h2{0, 0}, h2{0, 0}, h2{0, 0}};
#pragma unroll
  for (int k = 0; k < K; ++k) {
    const float sf = readlane_f(sffr[k >> 3], (k & 7) * 8);
    const _Float16 sh = (_Float16)sf;
    const h2 sf2 = h2{sh, sh};
    const h2 a = u2h2(xpb32[(size_t)jis[k] * 48 + l]);
    const h2 q = u2h2(xpb32[(size_t)jjs[k] * 48 + l]);
    accT[k & 3] = accT[k & 3] + (a + q);
    accX[k & 3] = habs2(a - q) * sf2 + accX[k & 3];
  }
  const float2 t0 = h22f2(accT[0]), t1 = h22f2(accT[1]);
  const float2 t2 = h22f2(accT[2]), t3 = h22f2(accT[3]);
  const float2 x0 = h22f2(accX[0]), x1 = h22f2(accX[1]);
  const float2 x2 = h22f2(accX[2]), x3 = h22f2(accX[3]);
  const float resx = (t0.x + t1.x) + (t2.x + t3.x) + (x0.x + x1.x) + (x2.x + x3.x);
  const float resy = (t0.y + t1.y) + (t2.y + t3.y) + (x0.y + x1.y) + (x2.y + x3.y);

  // ---- stage results in LDS, then block-coalesced store ------------------
  if (lane < 48) {
    ored[wave][2 * lane] = resx;
    ored[wave][2 * lane + 1] = resy;
  }
  __syncthreads();
  const int n0 = tile * 4;
  const int tid = threadIdx.x;
  {
    const int ch = tid >> 2, nn = tid & 3;  // ch 0..63
    out[((size_t)b * C + ch) * N + n0 + nn] = ored[nn][ch];
  }
  if (tid < 128) {
    const int t2i = 256 + tid;
    const int ch = t2i >> 2, nn = t2i & 3;  // ch 64..95
    out[((size_t)b * C + ch) * N + n0 + nn] = ored[nn][ch];
  }
}

// ---------------------------------------------------------------------------
// Fallback (only used if ws_size is too small): slow but correct (f32).
// ---------------------------------------------------------------------------
__global__ void fallback_kernel(const float* __restrict__ x,
                                const float* __restrict__ xp,
                                const int* __restrict__ e,
                                float* __restrict__ out) {
  const int gn = blockIdx.x * 64 + threadIdx.x;
  if (gn >= B * N) return;
  const int b = gn / N;
  const int n = gn - b * N;
  const float* xb = x + (size_t)b * C * N;
  const float* xpb = xp + (size_t)b * C * N;
  int ii[K], jj[K];
  float sff[K];
#pragma unroll
  for (int k = 0; k < K; ++k) {
    jj[k] = e[((size_t)(0 * B + b) * N + n) * K + k];
    ii[k] = e[((size_t)(1 * B + b) * N + n) * K + k];
    float si = 0, sj = 0, sii = 0, sjj = 0, sij = 0;
    for (int c = 0; c < C; ++c) {
      const float a = xb[(size_t)c * N + ii[k]];
      const float q = xb[(size_t)c * N + jj[k]];
      si += a; sj += q; sii += a * a; sjj += q * q; sij += a * q;
    }
    const float mi = si * (1.f / C), mj = sj * (1.f / C);
    const float vi = sii * (1.f / C) - mi * mi;
    const float vj = sjj * (1.f / C) - mj * mj;
    const float cov = sij * (1.f / C) - mi * mj;
    const float S1 = (2.f * mi * mj + C1c) / (mi * mi + mj * mj + C1c);
    const float S2 = (2.f * cov + C2c) / (vi + vj + C2c);
    sff[k] = 1.f - S1 * S2;
  }
  for (int c = 0; c < C; ++c) {
    float acc = 0.f;
#pragma unroll
    for (int k = 0; k < K; ++k) {
      const float a = xpb[(size_t)c * N + ii[k]];
      const float q = xpb[(size_t)c * N + jj[k]];
      acc += a + q + fabsf(a - q) * sff[k];
    }
    out[((size_t)b * C + c) * N + n] = acc;
  }
}

// ---------------------------------------------------------------------------
extern "C" void kernel_launch(void* const* d_in, const int* in_sizes, int n_in,
                              void* d_out, int out_size, void* d_ws, size_t ws_size,
                              hipStream_t stream) {
  const float* x = (const float*)d_in[0];
  const float* xp = (const float*)d_in[1];
  const int* e = (const int*)d_in[2];
  float* out = (float*)d_out;

  const size_t nBNC = (size_t)B * N * C;
  const size_t nBN = (size_t)B * N;
  const size_t need = 2 * nBNC * sizeof(ushort16) + nBN * sizeof(float2);

  if (ws_size >= need) {
    ushort16* xT = (ushort16*)d_ws;
    ushort16* xpT = xT + nBNC;
    float2* cstat = (float2*)(xpT + nBNC);

    fusedT_kernel<<<8 * (N / 32), 256, 0, stream>>>(x, xp, xT, xpT, cstat);
    ssim_main_kernel<<<(B * N) / 4, 256, 0, stream>>>(xT, xpT, cstat, e, out);
  } else {
    fallback_kernel<<<(B * N + 63) / 64, 64, 0, stream>>>(x, xp, e, out);
  }
}